// Round 10
// baseline (17.214 us; speedup 1.0000x reference)
//
#include <hip/hip_runtime.h>
#include <hip/hip_bf16.h>
#include <stdint.h>

// Problem constants (fixed by reference)
#define BB 4
#define LL 256
#define WW 256
#define HH 768
#define NL 10
#define LT 16           // L-rows per score block
#define WT 64           // W-cols per score block
#define ASTRIDE 776     // A_lds row stride in ushorts (97*8 -> 1552B, ~conflict-free)

typedef __attribute__((ext_vector_type(8))) short bf16x8;   // 8 bf16 (4 VGPRs)
typedef __attribute__((ext_vector_type(4))) float f32x4;    // MFMA C/D

__device__ inline unsigned short f2bf(float x) {            // RNE via HW cvt
    return __builtin_bit_cast(unsigned short, __float2bfloat16(x));
}
__device__ inline bf16x8 pack8(float4 a, float4 b) {
    union { bf16x8 v; unsigned short u[8]; } r;
    r.u[0] = f2bf(a.x); r.u[1] = f2bf(a.y); r.u[2] = f2bf(a.z); r.u[3] = f2bf(a.w);
    r.u[4] = f2bf(b.x); r.u[5] = f2bf(b.y); r.u[6] = f2bf(b.z); r.u[7] = f2bf(b.w);
    return r.v;
}

// ---------------------------------------------------------------------------
// K1: score. Block = (b, 16 L-rows, 64 W-cols); 512 threads, 8 waves.
// K-SPLIT: wave pair (wv, wv+4) computes the same 16x16 C-tile, each doing 12
// of the 24 k-steps; partials summed via LDS. -> 2 waves/SIMD latency hiding.
//  - A (hidden rows) staged once in LDS as bf16 (padded stride), 8-way split.
//  - B (gathered emb_a rows) direct fp32, depth-4 rotating prefetch.
//  - mask/label epilogue loads issued BEFORE the k-loop (hide cold-HBM lat).
//  - XCD swizzle: 16 lt-blocks sharing (b,wt) -> same XCD (L2-resident B).
// Writes UNNORMALIZED buckets s[16][10]; denominator D = sum_k s_k later.
// ---------------------------------------------------------------------------
__global__ __launch_bounds__(512, 1) void score_kernel(
    const int* __restrict__ word_seq,           // [B,W]
    const float* __restrict__ hidden,           // [B,L,H]
    const float* __restrict__ emb_a,            // [50000,H]
    const int* __restrict__ label,              // [B,L,W]
    const float* __restrict__ mask,             // [B,L,W]
    float* __restrict__ s_out)                  // [256 logical][16][10]
{
    __shared__ unsigned short A_lds[LT * ASTRIDE];   // 24832 B
    __shared__ float partial[4][64][4];              // 4096 B (hi-wave acc)
    __shared__ float s_lds[LT][NL];

    const int t    = threadIdx.x;
    const int wv   = t >> 6, lane = t & 63;
    const int ti   = wv & 3;                    // C-tile index (col group)
    const int kb   = (wv >> 2) * 12;            // k-range base: 0 or 12
    const int g    = lane >> 4, c = lane & 15;

    // ---- XCD-grouped swizzle decode (bijective on [0,256)) ----
    const int x    = blockIdx.x;
    const int G    = (x & 7) + 8 * (x >> 7);
    const int lt   = (x >> 3) & 15;
    const int b    = G >> 2, wt = G & 3;
    const int l0   = lt * LT;

    if (t < LT * NL) ((float*)s_lds)[t] = 0.f;

    // ---- stage A: 16 rows x 768 fp32 -> bf16 LDS, 1536 8-elem units ----
    #pragma unroll
    for (int i = 0; i < 3; ++i) {
        int idx = t + i * 512;
        int r = idx / 96, u = idx - r * 96;
        const float4* src = reinterpret_cast<const float4*>(
            hidden + ((size_t)(b * LL) + l0 + r) * HH + u * 8);
        float4 v0 = src[0], v1 = src[1];
        *reinterpret_cast<bf16x8*>(&A_lds[r * ASTRIDE + u * 8]) = pack8(v0, v1);
    }

    // ---- B pointer: one gathered emb_a row per (ti,c) ----
    const int wcol = wt * WT + ti * 16 + c;
    const int wrow = word_seq[b * WW + wcol];
    const float4* bp = reinterpret_cast<const float4*>(
        emb_a + (size_t)wrow * HH + g * 8);      // +8 f4 per k-step

    // ---- low waves: prefetch epilogue mask/label into regs (issue early) ----
    float mval[4]; int lval[4];
    if (kb == 0) {
        #pragma unroll
        for (int r = 0; r < 4; ++r) {
            size_t idx = ((size_t)(b * LL) + l0 + g * 4 + r) * WW + wcol;
            mval[r] = mask[idx];
            lval[r] = label[idx];
        }
    }

    // ---- depth-4 rotating prefetch for B over this wave's 12 k-steps ----
    float4 rb0[4], rb1[4];
    #pragma unroll
    for (int i = 0; i < 4; ++i) {
        rb0[i] = bp[(kb + i) * 8];
        rb1[i] = bp[(kb + i) * 8 + 1];
    }

    __syncthreads();    // A_lds staged, s_lds zeroed

    f32x4 acc = {0.f, 0.f, 0.f, 0.f};
    #pragma unroll
    for (int k = 0; k < 12; ++k) {
        const int s = k & 3;
        bf16x8 bv = pack8(rb0[s], rb1[s]);
        bf16x8 av = *reinterpret_cast<const bf16x8*>(
            &A_lds[c * ASTRIDE + (4 * (kb + k) + g) * 8]);
        if (k + 4 < 12) {
            rb0[s] = bp[(kb + k + 4) * 8];
            rb1[s] = bp[(kb + k + 4) * 8 + 1];
        }
        acc = __builtin_amdgcn_mfma_f32_16x16x32_bf16(av, bv, acc, 0, 0, 0);
    }

    // ---- k-split reduce: high wave -> LDS, low wave adds ----
    if (kb != 0)
        *reinterpret_cast<f32x4*>(&partial[ti][lane][0]) = acc;
    __syncthreads();

    if (kb == 0) {
        f32x4 other = *reinterpret_cast<const f32x4*>(&partial[ti][lane][0]);
        acc += other;

        // C/D layout (m89): col = lane&15 (w), row = (lane>>4)*4 + reg (l)
        const float scale = 0.03608439182435161f;  // 1/sqrt(768)
        #pragma unroll
        for (int r = 0; r < 4; ++r) {
            int lrow = g * 4 + r;
            float m = fminf(fmaxf(mval[r], 0.f), 1.f);
            float e = __expf(acc[r] * scale) * m;
            atomicAdd(&s_lds[lrow][lval[r]], e);
        }
    }
    __syncthreads();

    // logical slot (b,lt,wt) so combine's indexing is unchanged
    if (t < LT * NL) {
        size_t sidx = ((size_t)((b * 16 + lt) * 4 + wt)) * (LT * NL) + t;
        s_out[sidx] = ((float*)s_lds)[t];
    }
}

// ---------------------------------------------------------------------------
// K2: combine W-tile partials, normalize, 10-row epilogue + residual.
// Block = (b, 16 L-rows, 192 h-cols); grid 256, 192 threads (3 waves).
// ---------------------------------------------------------------------------
__global__ __launch_bounds__(192, 4) void combine_kernel(
    const float* __restrict__ s_in,     // [256][16][10]
    const float* __restrict__ hidden,   // [B,L,H]
    const float* __restrict__ emb_c,    // [10,H]
    float* __restrict__ out)            // [B,L,H]
{
    __shared__ float sp[LT][NL];
    __shared__ float inv[LT];
    const int t = threadIdx.x;
    const int bid = blockIdx.x;
    const int hq = bid & 3, lt = (bid >> 2) & 15, b = bid >> 6;
    const int l0 = lt * LT;
    const int h = hq * 192 + t;

    if (t < LT * NL) {
        size_t base = ((size_t)(b * 16 + lt)) * 4 * (LT * NL);  // wt=0 slot
        float v = 0.f;
        #pragma unroll
        for (int wt = 0; wt < 4; ++wt) v += s_in[base + wt * (LT * NL) + t];
        ((float*)sp)[t] = v;
    }
    __syncthreads();
    if (t < LT) {
        float d = 1e-10f;
        #pragma unroll
        for (int k = 0; k < NL; ++k) d += sp[t][k];
        inv[t] = 1.f / d;
    }
    __syncthreads();

    float ec[NL];
    #pragma unroll
    for (int k = 0; k < NL; ++k) ec[k] = emb_c[k * HH + h];
    #pragma unroll
    for (int r = 0; r < LT; ++r) {
        size_t base = ((size_t)(b * LL) + l0 + r) * HH + h;
        float acc = 0.f;
        #pragma unroll
        for (int k = 0; k < NL; ++k) acc = fmaf(sp[r][k], ec[k], acc);
        out[base] = hidden[base] + acc * inv[r];
    }
}

extern "C" void kernel_launch(void* const* d_in, const int* in_sizes, int n_in,
                              void* d_out, int out_size, void* d_ws, size_t ws_size,
                              hipStream_t stream) {
    const int*   word_seq = (const int*)d_in[0];
    const float* hidden   = (const float*)d_in[1];
    const int*   label    = (const int*)d_in[2];
    const float* mask     = (const float*)d_in[3];
    const float* emb_a    = (const float*)d_in[4];
    const float* emb_c    = (const float*)d_in[5];
    float*       out      = (float*)d_out;

    float* s_out = (float*)d_ws;   // 256*160 fp32 = 160 KB scratch

    score_kernel<<<BB * 16 * 4, 512, 0, stream>>>(
        word_seq, hidden, emb_a, label, mask, s_out);
    combine_kernel<<<BB * 16 * 4, 192, 0, stream>>>(s_out, hidden, emb_c, out);
}